// Round 1
// baseline (59.844 us; speedup 1.0000x reference)
//
#include <hip/hip_runtime.h>
#include <math.h>

// Problem constants (from reference): B=8, T=512, DIM=9, UPP=512
#define BB 8
#define TT 512
#define DIMN 9
#define UPP 512
#define LL (TT * UPP)            // 262144 samples
#define SRATE 48000.0

__device__ __forceinline__ double dfrac(double x) { return x - floor(x); }

// Kernel 1: per (b,d) frame-level phase scan.
// grid = B*DIM blocks, block = T threads. Each thread = one frame t.
// Outputs (all double, laid out [b][t][d] for coalesced reads in kernel 2):
//   rp[b][t][d] = frac(rad) = per-sample phase increment (mod 1)
//   cf[b][t][d] = frac(phase prefix BEFORE frame t) = frac(UPP * sum_{s<t} rp_s)
__global__ void frame_scan_kernel(const float* __restrict__ f0,
                                  const float* __restrict__ rand_ini,
                                  double* __restrict__ rp_out,
                                  double* __restrict__ cf_out) {
    const int bd = blockIdx.x;
    const int b = bd / DIMN;
    const int d = bd % DIMN;
    const int t = threadIdx.x;

    double f = (double)f0[b * TT + t];
    // rad = (f0*mult/SR) % 1 ; f0<=400, mult<=9 -> < 0.075, first mod is identity
    double raw = f * (double)(d + 1) * (1.0 / SRATE);
    if (t == 0) raw += (double)rand_ini[b * DIMN + d];  // rand_ini added after first mod
    double rp = dfrac(raw);                             // rad_up = repeat(rad) % 1
    rp_out[(b * TT + t) * DIMN + d] = rp;

    // exclusive prefix sum of w_t = UPP * rp_t  (max total ~ 2.8e5, exact in f64)
    __shared__ double sh[TT];
    sh[t] = (double)UPP * rp;
    __syncthreads();
    for (int off = 1; off < TT; off <<= 1) {
        double add = (t >= off) ? sh[t - off] : 0.0;
        __syncthreads();
        sh[t] += add;
        __syncthreads();
    }
    double C = (t == 0) ? 0.0 : sh[t - 1];
    cf_out[(b * TT + t) * DIMN + d] = dfrac(C);
}

// Kernel 2: one thread per output element (b, l, d).
// phase(l = t*UPP + k) mod 1 = frac(cf[b][t][d] + (k+1) * rp[b][t][d])
// (the reference's wrap/shift corrections are integers -> irrelevant under sin(2*pi*x))
__global__ void sine_out_kernel(const float* __restrict__ f0,
                                const float* __restrict__ noise_randn,
                                const double* __restrict__ rp,
                                const double* __restrict__ cf,
                                float* __restrict__ out0,   // sine_waves [B,L,DIM]
                                float* __restrict__ out1,   // uv         [B,L,1]
                                float* __restrict__ out2) { // noise      [B,L,DIM]
    long long idx = (long long)blockIdx.x * blockDim.x + threadIdx.x;
    const long long total = (long long)BB * LL * DIMN;
    if (idx >= total) return;

    int d = (int)(idx % DIMN);
    long long bl = idx / DIMN;
    int l = (int)(bl % LL);
    int b = (int)(bl / LL);
    int t = l >> 9;            // l / UPP
    int k = l & (UPP - 1);     // l % UPP

    int fidx = (b * TT + t) * DIMN + d;
    double r = rp[fidx];
    double c = cf[fidx];
    double ph = c + (double)(k + 1) * r;
    float frac = (float)dfrac(ph);

    float s = sinf(6.28318530717958647692f * frac) * 0.1f;

    float f0v = f0[b * TT + t];
    float uvf = (f0v > 0.0f) ? 1.0f : 0.0f;
    float namp = (f0v > 0.0f) ? 0.003f : (0.1f / 3.0f);
    float nz = namp * noise_randn[idx];

    out0[idx] = s * uvf + nz;
    out2[idx] = nz;
    if (d == 0) out1[(long long)b * LL + l] = uvf;
}

extern "C" void kernel_launch(void* const* d_in, const int* in_sizes, int n_in,
                              void* d_out, int out_size, void* d_ws, size_t ws_size,
                              hipStream_t stream) {
    const float* f0          = (const float*)d_in[0];   // [B, T]
    const float* rand_ini    = (const float*)d_in[1];   // [B, DIM]
    const float* noise_randn = (const float*)d_in[2];   // [B, L, DIM]
    // d_in[3] = upp (scalar 512) — hardcoded

    // workspace: rp (B*T*DIM doubles) then cf (B*T*DIM doubles) = 590 KB total
    double* rp = (double*)d_ws;
    double* cf = rp + (size_t)BB * TT * DIMN;

    float* out0 = (float*)d_out;                                   // B*L*DIM
    float* out1 = out0 + (size_t)BB * LL * DIMN;                   // B*L
    float* out2 = out1 + (size_t)BB * LL;                          // B*L*DIM

    frame_scan_kernel<<<BB * DIMN, TT, 0, stream>>>(f0, rand_ini, rp, cf);

    const long long total = (long long)BB * LL * DIMN;  // 18,874,368
    const int block = 256;
    const long long grid = (total + block - 1) / block;
    sine_out_kernel<<<(int)grid, block, 0, stream>>>(f0, noise_randn, rp, cf,
                                                     out0, out1, out2);
}

// Round 2
// 47.610 us; speedup vs baseline: 1.2570x; 1.2570x over previous
//
#include <hip/hip_runtime.h>
#include <math.h>

// Problem constants: B=8, T=512, DIM=9, UPP=512
#define BB 8
#define TT 512
#define DIMN 9
#define UPP 512
#define LL (TT * UPP)                     // 262144 = 2^18
#define TOTAL (BB * LL * DIMN)            // 18,874,368 (divisible by 1024)
#define SRATE 48000.0

__device__ __forceinline__ double dfrac(double x) { return x - floor(x); }

// Kernel 1: per (b,d) frame-level phase scan in f64, outputs f32.
//   rp[b][t][d] = frac(rad)                 (per-sample phase increment, revolutions)
//   cf[b][t][d] = frac(UPP * sum_{s<t} rp)  (phase before frame t, mod 1)
__global__ void frame_scan_kernel(const float* __restrict__ f0,
                                  const float* __restrict__ rand_ini,
                                  float* __restrict__ rp_out,
                                  float* __restrict__ cf_out) {
    const int bd = blockIdx.x;
    const int b = bd / DIMN;
    const int d = bd % DIMN;
    const int t = threadIdx.x;

    double f = (double)f0[b * TT + t];
    double raw = f * (double)(d + 1) * (1.0 / SRATE);   // < 0.075, first %1 is identity
    if (t == 0) raw += (double)rand_ini[b * DIMN + d];
    double rp = dfrac(raw);
    rp_out[(b * TT + t) * DIMN + d] = (float)rp;

    __shared__ double sh[TT];
    sh[t] = (double)UPP * rp;
    __syncthreads();
    for (int off = 1; off < TT; off <<= 1) {
        double add = (t >= off) ? sh[t - off] : 0.0;
        __syncthreads();
        sh[t] += add;
        __syncthreads();
    }
    double C = (t == 0) ? 0.0 : sh[t - 1];
    cf_out[(b * TT + t) * DIMN + d] = (float)dfrac(C);
}

// Kernel 3: uv output [B, L], float4 writes (4 samples share the same frame t).
__global__ void uv_kernel(const float* __restrict__ f0, float* __restrict__ out1) {
    unsigned i4 = (blockIdx.x * blockDim.x + threadIdx.x) * 4u;   // < B*L
    unsigned b = i4 >> 18;            // / LL
    unsigned l = i4 & (LL - 1u);
    unsigned t = l >> 9;              // / UPP
    float uvf = (f0[b * TT + t] > 0.0f) ? 1.0f : 0.0f;
    float4 v = make_float4(uvf, uvf, uvf, uvf);
    *reinterpret_cast<float4*>(out1 + i4) = v;
}

// Kernel 2: 4 consecutive flat elements per thread. All f32.
// frac(phase) = fract(cf[b][t][d] + (k+1)*rp[b][t][d]);  sin via v_sin_f32 (revolutions).
__global__ void __launch_bounds__(256) sine_out_kernel(
        const float* __restrict__ f0,
        const float* __restrict__ noise_randn,
        const float* __restrict__ rp,
        const float* __restrict__ cf,
        float* __restrict__ out0,
        float* __restrict__ out2) {
    unsigned base = (blockIdx.x * blockDim.x + threadIdx.x) * 4u;

    float4 nz4 = *reinterpret_cast<const float4*>(noise_randn + base);
    const float* nzp = &nz4.x;

    unsigned d  = base % 9u;
    unsigned bl = base / 9u;          // b*LL + l

    float o0[4], o2[4];
#pragma unroll
    for (int j = 0; j < 4; ++j) {
        unsigned b = bl >> 18;
        unsigned l = bl & (LL - 1u);
        unsigned t = l >> 9;
        unsigned k = l & 511u;
        unsigned fidx = (b * TT + t) * DIMN + d;

        float r = rp[fidx];
        float c = cf[fidx];
        float ph = fmaf((float)(k + 1), r, c);
        float ff = __builtin_amdgcn_fractf(ph);          // v_fract_f32
        float s  = __builtin_amdgcn_sinf(ff) * 0.1f;     // v_sin_f32: sin(2*pi*x)

        float f0v = f0[b * TT + t];
        bool  v   = f0v > 0.0f;
        float nz  = (v ? 0.003f : (0.1f / 3.0f)) * nzp[j];
        o0[j] = (v ? s : 0.0f) + nz;
        o2[j] = nz;

        if (++d == 9u) { d = 0u; ++bl; }
    }
    *reinterpret_cast<float4*>(out0 + base) = make_float4(o0[0], o0[1], o0[2], o0[3]);
    *reinterpret_cast<float4*>(out2 + base) = make_float4(o2[0], o2[1], o2[2], o2[3]);
}

extern "C" void kernel_launch(void* const* d_in, const int* in_sizes, int n_in,
                              void* d_out, int out_size, void* d_ws, size_t ws_size,
                              hipStream_t stream) {
    const float* f0          = (const float*)d_in[0];   // [B, T]
    const float* rand_ini    = (const float*)d_in[1];   // [B, DIM]
    const float* noise_randn = (const float*)d_in[2];   // [B, L, DIM]
    // d_in[3] = upp (scalar 512) — hardcoded

    float* rp = (float*)d_ws;                           // B*T*DIM f32
    float* cf = rp + (size_t)BB * TT * DIMN;            // B*T*DIM f32  (total 295 KB)

    float* out0 = (float*)d_out;                        // [B, L, DIM]
    float* out1 = out0 + (size_t)BB * LL * DIMN;        // [B, L]
    float* out2 = out1 + (size_t)BB * LL;               // [B, L, DIM]

    frame_scan_kernel<<<BB * DIMN, TT, 0, stream>>>(f0, rand_ini, rp, cf);

    const int block = 256;
    const unsigned grid2 = TOTAL / 4 / block;           // 18432
    sine_out_kernel<<<grid2, block, 0, stream>>>(f0, noise_randn, rp, cf, out0, out2);

    const unsigned grid3 = (BB * LL) / 4 / block;       // 2048
    uv_kernel<<<grid3, block, 0, stream>>>(f0, out1);
}

// Round 3
// 45.511 us; speedup vs baseline: 1.3149x; 1.0461x over previous
//
#include <hip/hip_runtime.h>
#include <math.h>

// Problem constants: B=8, T=512, DIM=9, UPP=512
#define BB 8
#define TT 512
#define DIMN 9
#define UPP 512
#define LL (TT * UPP)                     // 262144 = 2^18
#define TOTAL (BB * LL * DIMN)            // 18,874,368
#define SRATE 48000.0

__device__ __forceinline__ double dfrac(double x) { return x - floor(x); }

// Kernel 1: frame-level phase scan, one WAVE per (b,d), no barriers.
// Lane handles 8 consecutive frames; 6-step shuffle scan across the wave.
//   rp[b][t][d] = frac(rad)                 (per-sample increment, revolutions)
//   cf[b][t][d] = frac(UPP * sum_{s<t} rp)  (phase before frame t, mod 1)
__global__ void __launch_bounds__(256) frame_scan_wave(
        const float* __restrict__ f0,
        const float* __restrict__ rand_ini,
        float* __restrict__ rp_out,
        float* __restrict__ cf_out) {
    const int wave = blockIdx.x * 4 + (threadIdx.x >> 6);   // 0..71
    const int lane = threadIdx.x & 63;
    if (wave >= BB * DIMN) return;
    const int b = wave / DIMN;
    const int d = wave % DIMN;
    const int t0 = lane * 8;

    float4 fA = *reinterpret_cast<const float4*>(f0 + b * TT + t0);
    float4 fB = *reinterpret_cast<const float4*>(f0 + b * TT + t0 + 4);
    float fv[8] = {fA.x, fA.y, fA.z, fA.w, fB.x, fB.y, fB.z, fB.w};

    const double mult = (double)(d + 1) * (1.0 / SRATE);
    double rpj[8], pex[8];
    double s = 0.0;
#pragma unroll
    for (int j = 0; j < 8; ++j) {
        double raw = (double)fv[j] * mult;                  // < 0.075, first %1 identity
        if (lane == 0 && j == 0) raw += (double)rand_ini[b * DIMN + d];
        double rp = dfrac(raw);
        rpj[j] = rp;
        pex[j] = s;                                         // exclusive within-lane prefix
        s += (double)UPP * rp;
    }
    // inclusive scan of per-lane sums across 64 lanes
    double incl = s;
#pragma unroll
    for (int off = 1; off < 64; off <<= 1) {
        double up = __shfl_up(incl, off);
        if (lane >= off) incl += up;
    }
    const double E = incl - s;                              // exclusive wave prefix
#pragma unroll
    for (int j = 0; j < 8; ++j) {
        int fidx = (b * TT + t0 + j) * DIMN + d;
        rp_out[fidx] = (float)rpj[j];
        cf_out[fidx] = (float)dfrac(E + pex[j]);
    }
}

// Kernel 2: 4 consecutive flat elements per thread, all f32, v_fract+v_sin.
// First 2048 blocks additionally write one float4 of uv (out1).
__global__ void __launch_bounds__(256) sine_out_kernel(
        const float* __restrict__ f0,
        const float* __restrict__ noise_randn,
        const float* __restrict__ rp,
        const float* __restrict__ cf,
        float* __restrict__ out0,
        float* __restrict__ out1,
        float* __restrict__ out2) {
    unsigned gid  = blockIdx.x * blockDim.x + threadIdx.x;
    unsigned base = gid * 4u;

    float4 nz4 = *reinterpret_cast<const float4*>(noise_randn + base);
    const float* nzp = &nz4.x;

    unsigned d  = base % 9u;
    unsigned bl = base / 9u;          // b*LL + l

    float o0[4], o2[4];
#pragma unroll
    for (int j = 0; j < 4; ++j) {
        unsigned b = bl >> 18;
        unsigned l = bl & (LL - 1u);
        unsigned t = l >> 9;
        unsigned k = l & 511u;
        unsigned fidx = (b * TT + t) * DIMN + d;

        float r = rp[fidx];
        float c = cf[fidx];
        float ph = fmaf((float)(k + 1), r, c);
        float ff = __builtin_amdgcn_fractf(ph);          // v_fract_f32
        float s  = __builtin_amdgcn_sinf(ff) * 0.1f;     // v_sin_f32: sin(2*pi*x)

        float f0v = f0[b * TT + t];
        bool  v   = f0v > 0.0f;
        float nz  = (v ? 0.003f : (0.1f / 3.0f)) * nzp[j];
        o0[j] = (v ? s : 0.0f) + nz;
        o2[j] = nz;

        if (++d == 9u) { d = 0u; ++bl; }
    }
    *reinterpret_cast<float4*>(out0 + base) = make_float4(o0[0], o0[1], o0[2], o0[3]);
    *reinterpret_cast<float4*>(out2 + base) = make_float4(o2[0], o2[1], o2[2], o2[3]);

    // fused uv: B*L/4 = 524288 float4 stores, done by the first 2048 blocks
    if (gid < (BB * LL) / 4u) {
        unsigned i4 = gid * 4u;                  // 4 samples, same frame (512%4==0)
        unsigned b = i4 >> 18;
        unsigned l = i4 & (LL - 1u);
        unsigned t = l >> 9;
        float uvf = (f0[b * TT + t] > 0.0f) ? 1.0f : 0.0f;
        *reinterpret_cast<float4*>(out1 + i4) = make_float4(uvf, uvf, uvf, uvf);
    }
}

extern "C" void kernel_launch(void* const* d_in, const int* in_sizes, int n_in,
                              void* d_out, int out_size, void* d_ws, size_t ws_size,
                              hipStream_t stream) {
    const float* f0          = (const float*)d_in[0];   // [B, T]
    const float* rand_ini    = (const float*)d_in[1];   // [B, DIM]
    const float* noise_randn = (const float*)d_in[2];   // [B, L, DIM]
    // d_in[3] = upp (scalar 512) — hardcoded

    float* rp = (float*)d_ws;                           // B*T*DIM f32
    float* cf = rp + (size_t)BB * TT * DIMN;            // B*T*DIM f32

    float* out0 = (float*)d_out;                        // [B, L, DIM]
    float* out1 = out0 + (size_t)BB * LL * DIMN;        // [B, L]
    float* out2 = out1 + (size_t)BB * LL;               // [B, L, DIM]

    frame_scan_wave<<<18, 256, 0, stream>>>(f0, rand_ini, rp, cf);

    const int block = 256;
    const unsigned grid2 = TOTAL / 4 / block;           // 18432
    sine_out_kernel<<<grid2, block, 0, stream>>>(f0, noise_randn, rp, cf,
                                                 out0, out1, out2);
}